// Round 3
// baseline (276.299 us; speedup 1.0000x reference)
//
#include <hip/hip_runtime.h>
#include <math.h>

// Problem constants (match reference file).
#define BATCH 256
#define VOCAB 128000
#define HIST  2048
#define EPS_T 1e-5f

// --- fused scan: 5 segments/row, software-pipelined chunk loop ---
#define SEGS 5
#define SEG_ELEMS (VOCAB / SEGS)          // 25600 elements per segment
#define SEG_VEC   (SEG_ELEMS / 4)         // 6400 float4s
#define SEG_WORDS (SEG_ELEMS / 32)        // 800 mask words per segment
#define BBLOCK 256
#define BWAVES (BBLOCK / 64)
#define NCHUNK (SEG_ELEMS / (BBLOCK * 4)) // 25 float4-chunks per thread
#define PF 4                              // prefetch depth (chunks in flight)

// Order-preserving f32 -> u32 transform (no NaNs in this problem).
__device__ __forceinline__ unsigned fkey(float f) {
    unsigned b = __float_as_uint(f);
    return (b & 0x80000000u) ? ~b : (b | 0x80000000u);
}

__device__ __forceinline__ void upd(float s, int idx, float& best, int& besti) {
    if (s > best || (s == best && idx < besti)) { best = s; besti = idx; }
}

__device__ __forceinline__ void body4(float4 l, unsigned w, int sh, float pen,
                                      int idx0, float& best, int& besti) {
    float e[4] = {l.x, l.y, l.z, l.w};
    #pragma unroll
    for (int j = 0; j < 4; j++) {
        float present = (float)((w >> (sh + j)) & 1u);
        float p = e[j] - pen * present;           // exact: present in {0,1}
        upd(p, idx0 + j, best, besti);
    }
}

__device__ __forceinline__ void body4s(float4 l, float4 g, unsigned w, int sh,
                                       float pen, float temp,
                                       int idx0, float& best, int& besti) {
    float e[4]  = {l.x, l.y, l.z, l.w};
    float gv[4] = {g.x, g.y, g.z, g.w};
    #pragma unroll
    for (int j = 0; j < 4; j++) {
        float present = (float)((w >> (sh + j)) & 1u);
        float p = e[j] - pen * present;
        float s = p / temp + gv[j];               // reference op order, IEEE div
        upd(s, idx0 + j, best, besti);
    }
}

__device__ __forceinline__ void setbit(int t, int segBase, unsigned* smask) {
    unsigned u = (unsigned)(t - segBase);
    if (u < (unsigned)SEG_ELEMS)
        atomicOr(&smask[u >> 5], 1u << (u & 31));
}

// One block per (row, segment): 1280 blocks = 5 per CU, all co-resident.
// Phase 1 builds the 800-word presence mask in LDS (once per 25600 elems).
// Phase 2 is a fully-unrolled software pipeline: chunk k+PF is issued while
// chunk k is consumed -- load->use distance is structural, so the compiler
// must keep PF chunks in flight (unlike the flat burst, which rounds 0-2
// proved it sinks; VGPR_Count is the diagnostic).
__global__ __launch_bounds__(BBLOCK, 1) void fused_scan(
    const float* __restrict__ logits,        // [B, V]
    const float* __restrict__ gumbel,        // [B, V]
    const int*   __restrict__ token_ids,     // [B, L]
    const float* __restrict__ penalties,     // [B]
    const float* __restrict__ temps,         // [B]
    unsigned long long* __restrict__ keys)   // [B] packed (fkey(val)<<32)|~idx
{
    __shared__ unsigned smask[SEG_WORDS];    // 3.2 KB
    __shared__ float wval[BWAVES];
    __shared__ int   widx[BWAVES];

    const int blk = blockIdx.x;
    const int b   = blk / SEGS;
    const int seg = blk - b * SEGS;
    const int tid = threadIdx.x;

    const float pen    = penalties[b];
    const float temp   = temps[b];
    const bool  greedy = (temp < EPS_T);

    const int segBase = seg * SEG_ELEMS;

    // ---- Phase 1: presence mask ----
    // 2048 tokens / 256 threads = 8 each = two int4 loads per thread
    const int4* rt = (const int4*)(token_ids + (size_t)b * HIST);
    int4 ta = rt[tid];
    int4 tb = rt[tid + BBLOCK];

    #pragma unroll
    for (int i = tid; i < SEG_WORDS; i += BBLOCK) smask[i] = 0u;
    __syncthreads();                          // zeros visible (+ token loads landed)

    setbit(ta.x, segBase, smask); setbit(ta.y, segBase, smask);
    setbit(ta.z, segBase, smask); setbit(ta.w, segBase, smask);
    setbit(tb.x, segBase, smask); setbit(tb.y, segBase, smask);
    setbit(tb.z, segBase, smask); setbit(tb.w, segBase, smask);
    __syncthreads();                          // mask complete

    // ---- Phase 2: pipelined scan ----
    const float4* lg = (const float4*)(logits + (size_t)b * VOCAB) + seg * SEG_VEC;
    const float4* gm = (const float4*)(gumbel + (size_t)b * VOCAB) + seg * SEG_VEC;

    float best  = -INFINITY;
    int   besti = 0x7fffffff;
    const int sh    = (tid * 4) & 31;         // uniform across k (stride 1024 elems)
    const int abs0  = segBase + tid * 4;
    const int wbase = tid >> 3;               // mask word idx, stride 32 per k

    if (greedy) {
        float4 lb[NCHUNK];
        #pragma unroll
        for (int k = 0; k < PF; ++k) lb[k] = lg[tid + k * BBLOCK];
        #pragma unroll
        for (int k = 0; k < NCHUNK; ++k) {
            if (k + PF < NCHUNK) lb[k + PF] = lg[tid + (k + PF) * BBLOCK];
            __builtin_amdgcn_sched_barrier(0);   // pin: issue k+PF before body k
            unsigned w = smask[wbase + 32 * k];
            body4(lb[k], w, sh, pen, abs0 + k * BBLOCK * 4, best, besti);
        }
    } else {
        float4 lb[NCHUNK], gb[NCHUNK];
        #pragma unroll
        for (int k = 0; k < PF; ++k) {
            lb[k] = lg[tid + k * BBLOCK];
            gb[k] = gm[tid + k * BBLOCK];
        }
        #pragma unroll
        for (int k = 0; k < NCHUNK; ++k) {
            if (k + PF < NCHUNK) {
                lb[k + PF] = lg[tid + (k + PF) * BBLOCK];
                gb[k + PF] = gm[tid + (k + PF) * BBLOCK];
            }
            __builtin_amdgcn_sched_barrier(0);   // pin: issue k+PF before body k
            unsigned w = smask[wbase + 32 * k];
            body4s(lb[k], gb[k], w, sh, pen, temp,
                   abs0 + k * BBLOCK * 4, best, besti);
        }
    }

    // wave argmax reduction (64 lanes), first-index tie-break
    #pragma unroll
    for (int off = 32; off > 0; off >>= 1) {
        float ov = __shfl_down(best, off, 64);
        int   oi = __shfl_down(besti, off, 64);
        if (ov > best || (ov == best && oi < besti)) { best = ov; besti = oi; }
    }
    const int wave = tid >> 6, lane = tid & 63;
    if (lane == 0) { wval[wave] = best; widx[wave] = besti; }
    __syncthreads();

    if (tid == 0) {
        #pragma unroll
        for (int wv = 1; wv < BWAVES; wv++) {
            if (wval[wv] > best || (wval[wv] == best && widx[wv] < besti)) {
                best = wval[wv]; besti = widx[wv];
            }
        }
        // pack: bigger value wins; equal value -> max(~idx) = min idx (numpy tie-break)
        unsigned long long key =
            ((unsigned long long)fkey(best) << 32) | (unsigned)(~besti);
        atomicMax(keys + b, key);              // device-scope, 5 updates/row
    }
}

__global__ void decode_kernel(const unsigned long long* __restrict__ keys,
                              int* __restrict__ out)
{
    const int b = threadIdx.x;                 // 256 threads, one per row
    out[b] = (int)(~(unsigned)keys[b]);
}

extern "C" void kernel_launch(void* const* d_in, const int* in_sizes, int n_in,
                              void* d_out, int out_size, void* d_ws, size_t ws_size,
                              hipStream_t stream) {
    const float* logits    = (const float*)d_in[0];
    const int*   token_ids = (const int*)d_in[1];
    const float* penalties = (const float*)d_in[2];
    const float* temps     = (const float*)d_in[3];
    const float* gumbel    = (const float*)d_in[4];
    int* out = (int*)d_out;

    unsigned long long* keys = (unsigned long long*)d_ws;   // 2 KB

    // keys = 0 is below every real packed key (fkey of any finite float is
    // >= 0x00800000-ish > 0), so memset-0 is a valid -inf init.
    hipMemsetAsync(keys, 0, BATCH * sizeof(unsigned long long), stream);

    fused_scan<<<BATCH * SEGS, BBLOCK, 0, stream>>>(logits, gumbel, token_ids,
                                                    penalties, temps, keys);
    decode_kernel<<<1, BATCH, 0, stream>>>(keys, out);
}

// Round 4
// 275.715 us; speedup vs baseline: 1.0021x; 1.0021x over previous
//
#include <hip/hip_runtime.h>
#include <math.h>

// Problem constants (match reference file).
#define BATCH 256
#define VOCAB 128000
#define HIST  2048
#define EPS_T 1e-5f

// --- fused scan: 5 segments/row, inline-asm pipelined chunk loop ---
#define SEGS 5
#define SEG_ELEMS (VOCAB / SEGS)          // 25600 elements per segment
#define SEG_VEC   (SEG_ELEMS / 4)         // 6400 float4s
#define SEG_WORDS (SEG_ELEMS / 32)        // 800 mask words per segment
#define BBLOCK 256
#define BWAVES (BBLOCK / 64)
#define NCHUNK (SEG_ELEMS / (BBLOCK * 4)) // 25 float4-chunks per thread
#define PF 4                              // chunk-pairs kept in flight

typedef float f32x4 __attribute__((ext_vector_type(4)));

// Volatile asm load: the compiler CANNOT sink this to its use (rounds 0-3
// proved it sinks every C-level load, VGPR stuck at 32-36). Issue order among
// these is program order; no automatic s_waitcnt is generated for them -- we
// count vmcnt by hand (T4 pattern). "=&v": dst must not alias the addr pair.
__device__ __forceinline__ void gload(f32x4& dst, const f32x4* addr) {
    asm volatile("global_load_dwordx4 %0, %1, off"
                 : "=&v"(dst) : "v"(addr) : "memory");
}

// Order-preserving f32 -> u32 transform (no NaNs in this problem).
__device__ __forceinline__ unsigned fkey(float f) {
    unsigned b = __float_as_uint(f);
    return (b & 0x80000000u) ? ~b : (b | 0x80000000u);
}

__device__ __forceinline__ void upd(float s, int idx, float& best, int& besti) {
    if (s > best || (s == best && idx < besti)) { best = s; besti = idx; }
}

__device__ __forceinline__ void body4(f32x4 l, unsigned w, int sh, float pen,
                                      int idx0, float& best, int& besti) {
    #pragma unroll
    for (int j = 0; j < 4; j++) {
        float present = (float)((w >> (sh + j)) & 1u);
        float p = l[j] - pen * present;           // exact: present in {0,1}
        upd(p, idx0 + j, best, besti);
    }
}

__device__ __forceinline__ void body4s(f32x4 l, f32x4 g, unsigned w, int sh,
                                       float pen, float temp,
                                       int idx0, float& best, int& besti) {
    #pragma unroll
    for (int j = 0; j < 4; j++) {
        float present = (float)((w >> (sh + j)) & 1u);
        float p = l[j] - pen * present;
        float s = p / temp + g[j];                // reference op order, IEEE div
        upd(s, idx0 + j, best, besti);
    }
}

__device__ __forceinline__ void setbit(int t, int segBase, unsigned* smask) {
    unsigned u = (unsigned)(t - segBase);
    if (u < (unsigned)SEG_ELEMS)
        atomicOr(&smask[u >> 5], 1u << (u & 31));
}

// One block per (row, segment): 1280 blocks = 5 per CU, all co-resident.
// Phase 1 builds the 800-word presence mask in LDS. Phase 2 is an inline-asm
// software pipeline: PF chunk-pairs genuinely in flight, steady-state wait
// vmcnt(2*PF) -- never drained to 0 until the tail.
__global__ __launch_bounds__(BBLOCK, 1) void fused_scan(
    const float* __restrict__ logits,        // [B, V]
    const float* __restrict__ gumbel,        // [B, V]
    const int*   __restrict__ token_ids,     // [B, L]
    const float* __restrict__ penalties,     // [B]
    const float* __restrict__ temps,         // [B]
    unsigned long long* __restrict__ keys)   // [B] packed (fkey(val)<<32)|~idx
{
    __shared__ unsigned smask[SEG_WORDS];    // 3.2 KB
    __shared__ float wval[BWAVES];
    __shared__ int   widx[BWAVES];

    const int blk = blockIdx.x;
    const int b   = blk / SEGS;
    const int seg = blk - b * SEGS;
    const int tid = threadIdx.x;

    const float pen    = penalties[b];
    const float temp   = temps[b];
    const bool  greedy = (temp < EPS_T);

    const int segBase = seg * SEG_ELEMS;

    // ---- Phase 1: presence mask (compiler-managed loads; ends with a full
    // __syncthreads drain, so the asm loop below owns vmcnt exclusively) ----
    const int4* rt = (const int4*)(token_ids + (size_t)b * HIST);
    int4 ta = rt[tid];
    int4 tb = rt[tid + BBLOCK];

    #pragma unroll
    for (int i = tid; i < SEG_WORDS; i += BBLOCK) smask[i] = 0u;
    __syncthreads();                          // zeros visible

    setbit(ta.x, segBase, smask); setbit(ta.y, segBase, smask);
    setbit(ta.z, segBase, smask); setbit(ta.w, segBase, smask);
    setbit(tb.x, segBase, smask); setbit(tb.y, segBase, smask);
    setbit(tb.z, segBase, smask); setbit(tb.w, segBase, smask);
    __syncthreads();                          // mask complete; vmcnt drained

    // ---- Phase 2: asm-pipelined scan ----
    const f32x4* lgp = (const f32x4*)(logits + (size_t)b * VOCAB) + seg * SEG_VEC + tid;
    const f32x4* gmp = (const f32x4*)(gumbel + (size_t)b * VOCAB) + seg * SEG_VEC + tid;

    float best  = -INFINITY;
    int   besti = 0x7fffffff;
    const int sh    = (tid * 4) & 31;         // uniform across k (stride 1024 elems)
    const int abs0  = segBase + tid * 4;
    const int wbase = tid >> 3;               // mask word idx, stride 32 per k

    if (greedy) {
        f32x4 lb[NCHUNK];
        #pragma unroll
        for (int k = 0; k < PF; ++k) gload(lb[k], lgp + k * BBLOCK);
        #pragma unroll
        for (int k = 0; k < NCHUNK; ++k) {
            if (k + PF < NCHUNK) gload(lb[k + PF], lgp + (k + PF) * BBLOCK);
            const int rem = (k + PF < NCHUNK) ? PF : (NCHUNK - 1 - k);
            asm volatile("s_waitcnt vmcnt(%0)" :: "i"(rem) : "memory");
            __builtin_amdgcn_sched_barrier(0);   // rule #18: no hoist past the wait
            unsigned w = smask[wbase + 32 * k];
            body4(lb[k], w, sh, pen, abs0 + k * BBLOCK * 4, best, besti);
        }
    } else {
        f32x4 lb[NCHUNK], gb[NCHUNK];
        #pragma unroll
        for (int k = 0; k < PF; ++k) {
            gload(lb[k], lgp + k * BBLOCK);
            gload(gb[k], gmp + k * BBLOCK);
        }
        #pragma unroll
        for (int k = 0; k < NCHUNK; ++k) {
            if (k + PF < NCHUNK) {
                gload(lb[k + PF], lgp + (k + PF) * BBLOCK);
                gload(gb[k + PF], gmp + (k + PF) * BBLOCK);
            }
            const int rem = (k + PF < NCHUNK) ? PF : (NCHUNK - 1 - k);
            asm volatile("s_waitcnt vmcnt(%0)" :: "i"(2 * rem) : "memory");
            __builtin_amdgcn_sched_barrier(0);   // rule #18: no hoist past the wait
            unsigned w = smask[wbase + 32 * k];
            body4s(lb[k], gb[k], w, sh, pen, temp,
                   abs0 + k * BBLOCK * 4, best, besti);
        }
    }

    // wave argmax reduction (64 lanes), first-index tie-break
    #pragma unroll
    for (int off = 32; off > 0; off >>= 1) {
        float ov = __shfl_down(best, off, 64);
        int   oi = __shfl_down(besti, off, 64);
        if (ov > best || (ov == best && oi < besti)) { best = ov; besti = oi; }
    }
    const int wave = tid >> 6, lane = tid & 63;
    if (lane == 0) { wval[wave] = best; widx[wave] = besti; }
    __syncthreads();

    if (tid == 0) {
        #pragma unroll
        for (int wv = 1; wv < BWAVES; wv++) {
            if (wval[wv] > best || (wval[wv] == best && widx[wv] < besti)) {
                best = wval[wv]; besti = widx[wv];
            }
        }
        // pack: bigger value wins; equal value -> max(~idx) = min idx (numpy tie-break)
        unsigned long long key =
            ((unsigned long long)fkey(best) << 32) | (unsigned)(~besti);
        atomicMax(keys + b, key);              // device-scope, 5 updates/row
    }
}

__global__ void decode_kernel(const unsigned long long* __restrict__ keys,
                              int* __restrict__ out)
{
    const int b = threadIdx.x;                 // 256 threads, one per row
    out[b] = (int)(~(unsigned)keys[b]);
}

extern "C" void kernel_launch(void* const* d_in, const int* in_sizes, int n_in,
                              void* d_out, int out_size, void* d_ws, size_t ws_size,
                              hipStream_t stream) {
    const float* logits    = (const float*)d_in[0];
    const int*   token_ids = (const int*)d_in[1];
    const float* penalties = (const float*)d_in[2];
    const float* temps     = (const float*)d_in[3];
    const float* gumbel    = (const float*)d_in[4];
    int* out = (int*)d_out;

    unsigned long long* keys = (unsigned long long*)d_ws;   // 2 KB

    // keys = 0 is below every real packed key (fkey of any finite float > 0),
    // so memset-0 is a valid -inf init.
    hipMemsetAsync(keys, 0, BATCH * sizeof(unsigned long long), stream);

    fused_scan<<<BATCH * SEGS, BBLOCK, 0, stream>>>(logits, gumbel, token_ids,
                                                    penalties, temps, keys);
    decode_kernel<<<1, BATCH, 0, stream>>>(keys, out);
}

// Round 5
// 252.434 us; speedup vs baseline: 1.0945x; 1.0922x over previous
//
#include <hip/hip_runtime.h>
#include <math.h>

// Problem constants (match reference file).
#define BATCH 256
#define VOCAB 128000
#define HIST  2048
#define EPS_T 1e-5f

// --- barrier-free streaming scan ---
#define BBLOCK 256
#define BLOCKS_PER_ROW 8
#define GRID (BATCH * BLOCKS_PER_ROW)      // 2048 blocks = exactly 8/CU, co-resident
#define WAVES_PER_ROW (BLOCKS_PER_ROW * 4) // 32 autonomous waves per row
#define CHUNKS (VOCAB / 256)               // 500 chunks of 256 elems per row
#define MASK_WORDS (VOCAB / 32)            // 4000 words = 16 KB full-row mask

typedef float f32x4 __attribute__((ext_vector_type(4)));

// Order-preserving f32 -> u32 transform (no NaNs in this problem).
__device__ __forceinline__ unsigned fkey(float f) {
    unsigned b = __float_as_uint(f);
    return (b & 0x80000000u) ? ~b : (b | 0x80000000u);
}

__device__ __forceinline__ void upd(float s, int idx, float& best, int& besti) {
    if (s > best || (s == best && idx < besti)) { best = s; besti = idx; }
}

__device__ __forceinline__ void body4(f32x4 l, unsigned w, int sh, float pen,
                                      int idx0, float& best, int& besti) {
    #pragma unroll
    for (int j = 0; j < 4; j++) {
        float present = (float)((w >> (sh + j)) & 1u);
        float p = l[j] - pen * present;           // exact: present in {0,1}
        upd(p, idx0 + j, best, besti);
    }
}

__device__ __forceinline__ void body4s(f32x4 l, f32x4 g, unsigned w, int sh,
                                       float pen, float temp,
                                       int idx0, float& best, int& besti) {
    #pragma unroll
    for (int j = 0; j < 4; j++) {
        float present = (float)((w >> (sh + j)) & 1u);
        float p = l[j] - pen * present;
        float s = p / temp + g[j];                // reference op order, IEEE div
        upd(s, idx0 + j, best, besti);
    }
}

// One block per row-eighth. Prologue: full-row presence mask in LDS (16 KB),
// built once, two barriers total. Hot loop: each wave free-runs over its own
// chunks (c = wir + 32k), nontemporal loads (no L1/L2 allocation for
// zero-reuse data), no barriers, no LDS reduction -- one atomicMax per wave.
__global__ __launch_bounds__(BBLOCK, 1) void fused_scan(
    const float* __restrict__ logits,        // [B, V]
    const float* __restrict__ gumbel,        // [B, V]
    const int*   __restrict__ token_ids,     // [B, L]
    const float* __restrict__ penalties,     // [B]
    const float* __restrict__ temps,         // [B]
    unsigned long long* __restrict__ keys)   // [B] packed (fkey(val)<<32)|~idx
{
    __shared__ unsigned smask[MASK_WORDS];   // 16 KB: full row mask

    const int blk  = blockIdx.x;
    const int row  = blk >> 3;               // 8 blocks per row
    const int tid  = threadIdx.x;
    const int lane = tid & 63;
    const int wave = tid >> 6;
    const int wir  = ((blk & 7) << 2) | wave;   // wave-in-row, 0..31

    const float pen    = penalties[row];
    const float temp   = temps[row];
    const bool  greedy = (temp < EPS_T);

    // ---- prologue: full-row presence mask (the only barriers in the kernel) ----
    const int4* rt = (const int4*)(token_ids + (size_t)row * HIST);
    int4 ta = rt[tid];
    int4 tb = rt[tid + BBLOCK];              // 2048 tokens = 512 int4

    for (int i = tid; i < MASK_WORDS; i += BBLOCK) smask[i] = 0u;
    __syncthreads();                          // zeros visible

    atomicOr(&smask[ta.x >> 5], 1u << (ta.x & 31));
    atomicOr(&smask[ta.y >> 5], 1u << (ta.y & 31));
    atomicOr(&smask[ta.z >> 5], 1u << (ta.z & 31));
    atomicOr(&smask[ta.w >> 5], 1u << (ta.w & 31));
    atomicOr(&smask[tb.x >> 5], 1u << (tb.x & 31));
    atomicOr(&smask[tb.y >> 5], 1u << (tb.y & 31));
    atomicOr(&smask[tb.z >> 5], 1u << (tb.z & 31));
    atomicOr(&smask[tb.w >> 5], 1u << (tb.w & 31));
    __syncthreads();                          // mask complete

    // ---- hot loop: wave-autonomous streaming ----
    const f32x4* Lr = (const f32x4*)(logits + (size_t)row * VOCAB);
    const f32x4* Gr = (const f32x4*)(gumbel + (size_t)row * VOCAB);

    float best  = -INFINITY;
    int   besti = 0x7fffffff;
    const int sh    = (lane & 7) * 4;         // bit shift within mask word
    const int wsub  = lane >> 3;              // word-in-chunk (8 words/chunk)

    if (greedy) {
        int c = wir;
        f32x4 lc = __builtin_nontemporal_load(Lr + c * 64 + lane);
        while (true) {
            const int cn = c + 32;
            f32x4 ln = lc;
            if (cn < CHUNKS) ln = __builtin_nontemporal_load(Lr + cn * 64 + lane);
            const unsigned w = smask[c * 8 + wsub];
            body4(lc, w, sh, pen, c * 256 + lane * 4, best, besti);
            if (cn >= CHUNKS) break;
            lc = ln; c = cn;
        }
    } else {
        int c = wir;
        f32x4 lc = __builtin_nontemporal_load(Lr + c * 64 + lane);
        f32x4 gc = __builtin_nontemporal_load(Gr + c * 64 + lane);
        while (true) {
            const int cn = c + 32;
            f32x4 ln = lc, gn = gc;
            if (cn < CHUNKS) {
                ln = __builtin_nontemporal_load(Lr + cn * 64 + lane);
                gn = __builtin_nontemporal_load(Gr + cn * 64 + lane);
            }
            const unsigned w = smask[c * 8 + wsub];
            body4s(lc, gc, w, sh, pen, temp, c * 256 + lane * 4, best, besti);
            if (cn >= CHUNKS) break;
            lc = ln; gc = gn; c = cn;
        }
    }

    // wave argmax reduction (64 lanes), first-index tie-break
    #pragma unroll
    for (int off = 32; off > 0; off >>= 1) {
        float ov = __shfl_down(best, off, 64);
        int   oi = __shfl_down(besti, off, 64);
        if (ov > best || (ov == best && oi < besti)) { best = ov; besti = oi; }
    }

    // one device-scope atomic per wave (32 per row total)
    if (lane == 0) {
        unsigned long long key =
            ((unsigned long long)fkey(best) << 32) | (unsigned)(~besti);
        atomicMax(keys + row, key);
    }
}

__global__ void decode_kernel(const unsigned long long* __restrict__ keys,
                              int* __restrict__ out)
{
    const int b = threadIdx.x;                 // 256 threads, one per row
    out[b] = (int)(~(unsigned)keys[b]);
}

extern "C" void kernel_launch(void* const* d_in, const int* in_sizes, int n_in,
                              void* d_out, int out_size, void* d_ws, size_t ws_size,
                              hipStream_t stream) {
    const float* logits    = (const float*)d_in[0];
    const int*   token_ids = (const int*)d_in[1];
    const float* penalties = (const float*)d_in[2];
    const float* temps     = (const float*)d_in[3];
    const float* gumbel    = (const float*)d_in[4];
    int* out = (int*)d_out;

    unsigned long long* keys = (unsigned long long*)d_ws;   // 2 KB

    // keys = 0 is below every real packed key (fkey of any finite float > 0),
    // so memset-0 is a valid -inf init.
    hipMemsetAsync(keys, 0, BATCH * sizeof(unsigned long long), stream);

    fused_scan<<<GRID, BBLOCK, 0, stream>>>(logits, gumbel, token_ids,
                                            penalties, temps, keys);
    decode_kernel<<<1, BATCH, 0, stream>>>(keys, out);
}